// Round 13
// baseline (244.489 us; speedup 1.0000x reference)
//
#include <hip/hip_runtime.h>
#include <hip/hip_cooperative_groups.h>
#include <math.h>

namespace cg = cooperative_groups;

#define GRP   4
#define K     9
#define PAD   1
#define C_IN  64
#define CG    16
#define HH    128
#define WW    128
#define BB    4
#define HW    (HH*WW)
#define PP    116   // sm_om padded row stride (halfs), even

typedef __attribute__((ext_vector_type(8))) _Float16 f16x8;
typedef __attribute__((ext_vector_type(2))) _Float16 f16x2;
typedef __attribute__((ext_vector_type(4))) float    f32x4;

union F16Frag { f16x8 f; _Float16 h[8]; f16x2 p[4]; uint w[4]; uint4 q; };
union YX      { uint u; f16x2 h2; };

// ---------------- ws layout (superset: coop + R11 fallback) ------------------
#define PLANE      ((size_t)16 * HW)
#define XT_OFF     0
#define XT_BYTES   ((size_t)16 * HW * 16 * 2)               // 8,388,608
#define OMYX_OFF   XT_BYTES
#define OMYX_BYTES (9 * PLANE * 4)
#define OMM_OFF    (OMYX_OFF + OMYX_BYTES)
#define OMM_BYTES  (9 * PLANE * 2)
#define FR1_OFF    (OMM_OFF + OMM_BYTES)
#define FR1_BYTES  (14 * 64 * 16)
#define FR2_OFF    (FR1_OFF + FR1_BYTES)
#define FR2_BYTES  (20 * 64 * 16)
#define PART_OFF   (FR2_OFF + FR2_BYTES)
#define PART_BYTES (16 * 128 * 2 * 4)
#define NEED_BYTES (PART_OFF + PART_BYTES + 256)

// ---- make_frags: precompute MFMA weight fragments (proven) ------------------
__global__ __launch_bounds__(256) void make_frags(const float* __restrict__ w_om,
                                                  const float* __restrict__ dcn_w,
                                                  uint4* __restrict__ frags1,
                                                  uint4* __restrict__ frags2)
{
    const int t    = blockIdx.x * 256 + threadIdx.x;
    const int lane = t & 63;
    const int lr   = lane & 15, lj = lane >> 4;
    const int f    = t >> 6;
    F16Frag r;
    #pragma unroll
    for (int e = 0; e < 4; ++e) r.w[e] = 0u;
    if (f < 14) {
        const int nt = f >> 1, s = f & 1;
        const int col = nt * 16 + lr;
        const int g = col / 28, oo = col - 28 * g;
        if (oo < 27) {
            const float* src = w_om + (size_t)(g * 27 + oo) * C_IN + s * 32 + lj * 8;
            #pragma unroll
            for (int e = 0; e < 8; ++e) r.h[e] = (_Float16)src[e];
        }
        frags1[f * 64 + lane] = r.q;
    } else if (f < 34) {
        const int f2 = f - 14;
        const int g = f2 / 5, s = f2 - 5 * g;
        const int kp = 2 * s + (lj >> 1);
        const int cib = (lj & 1) * 8;
        if (kp < 9) {
            #pragma unroll
            for (int e = 0; e < 8; ++e)
                r.h[e] = (_Float16)dcn_w[((size_t)(g * CG + lr) * CG + cib + e) * 9 + kp];
        }
        frags2[f2 * 64 + lane] = r.q;
    }
}

// ---- cooperative fused kernel v2: 512 blocks x 256 thr (4 waves) ------------
// Block = (b,row). Phase A: om for all 4 groups of this row -> LDS (fp16,
// never HBM) + xt4 row write. grid.sync. Phase B: wave = group, 128 cols
// (8 tiles); taps from global xt4; PV MFMA; wave-shuffle partials -> ws.
// grid.sync. Phase C: stats + GN + exact GELU on register accumulators.
__global__ void __launch_bounds__(256, 4) dcn_coop(
    const float* __restrict__ x,
    const uint4* __restrict__ frags1,
    const uint4* __restrict__ frags2,
    const float* __restrict__ b_om,
    const float* __restrict__ dcn_b,
    const float* __restrict__ gn_w,
    const float* __restrict__ gn_b,
    const float* __restrict__ offset_scale,
    _Float16* __restrict__ xt4,
    float* __restrict__ partials,
    float* __restrict__ out)
{
    cg::grid_group grid = cg::this_grid();

    const int tid  = threadIdx.x;
    const int blk  = blockIdx.x;             // 512
    const int b    = blk >> 7;
    const int row  = blk & 127;
    const int wave = tid >> 6, lane = tid & 63;
    const int lr   = lane & 15, lj = lane >> 4;

    __shared__ _Float16 sm_om[128 * PP];     // 29,696 B
    __shared__ float smstat[8];

    const float scale = offset_scale[0];

    // ================= Phase A: om GEMM (2 tiles/wave) ======================
    {
        int g_[7], oo_[7];
        float bo_[7];
        #pragma unroll
        for (int nt = 0; nt < 7; ++nt) {
            const int col = nt * 16 + lr;
            const int g = col / 28, oo = col - 28 * g;
            g_[nt] = g; oo_[nt] = oo;
            bo_[nt] = (oo < 27) ? b_om[g * 27 + oo] : 0.0f;
        }

        #pragma unroll
        for (int t = 0; t < 2; ++t) {
            const int px0  = wave * 32 + t * 16;
            const int pixb = row * WW + px0 + lr;

            const float* xs = x + (size_t)b * C_IN * HW + pixb;
            F16Frag A0, A1;
            #pragma unroll
            for (int e = 0; e < 8; ++e) A0.h[e] = (_Float16)xs[(size_t)(lj * 8 + e) * HW];
            #pragma unroll
            for (int e = 0; e < 8; ++e) A1.h[e] = (_Float16)xs[(size_t)(32 + lj * 8 + e) * HW];

            const int g0 = (lj >> 1), g1 = 2 + (lj >> 1);
            const int hf = (lj & 1) * 8;
            *(uint4*)(xt4 + ((size_t)(b * 4 + g0) * HW + pixb) * 16 + hf) = A0.q;
            *(uint4*)(xt4 + ((size_t)(b * 4 + g1) * HW + pixb) * 16 + hf) = A1.q;

            #pragma unroll
            for (int nt = 0; nt < 7; ++nt) {
                F16Frag B0, B1;
                B0.q = frags1[(nt * 2 + 0) * 64 + lane];
                B1.q = frags1[(nt * 2 + 1) * 64 + lane];
                f32x4 C = {0, 0, 0, 0};
                C = __builtin_amdgcn_mfma_f32_16x16x32_f16(A0.f, B0.f, C, 0, 0, 0);
                C = __builtin_amdgcn_mfma_f32_16x16x32_f16(A1.f, B1.f, C, 0, 0, 0);
                const int g = g_[nt], oo = oo_[nt];
                if (oo < 27) {
                    #pragma unroll
                    for (int r = 0; r < 4; ++r) {
                        const int px = px0 + lj * 4 + r;
                        float v = C[r] + bo_[nt];
                        v = (oo < 18) ? v * scale : 1.0f / (1.0f + __expf(-v));
                        sm_om[px * PP + g * 28 + oo] = (_Float16)v;
                    }
                }
            }
        }
    }

    __syncthreads();
    __threadfence();
    grid.sync();

    // ================= Phase B: sampling + PV GEMM (g = wave) ===============
    const int g    = wave;
    const int hsel = lj & 1;
    f32x4 cacc[8];

    {
        F16Frag B2[5];
        #pragma unroll
        for (int s = 0; s < 5; ++s) B2[s].q = frags2[(g * 5 + s) * 64 + lane];
        const float cbias = dcn_b[g * CG + lr];

        const _Float16* xg = xt4 + (size_t)(b * 4 + g) * HW * 16 + hsel * 8;
        float gs = 0.0f, gss = 0.0f;

        #pragma unroll
        for (int tt = 0; tt < 8; ++tt) {
            const int col0 = tt * 16;
            const int px   = col0 + lr;          // this lane's A-row pixel

            f32x4 C2 = {cbias, cbias, cbias, cbias};
            #pragma unroll
            for (int s = 0; s < 5; ++s) {
                const int  kp  = 2 * s + (lj >> 1);
                const bool kok = (kp < 9);
                const int  kc  = kok ? kp : 8;

                YX yx; yx.u = *(const uint*)&sm_om[px * PP + g * 28 + 2 * kc];
                const float offy = (float)yx.h2[0];
                const float offx = (float)yx.h2[1];
                const float m    = kok ? (float)sm_om[px * PP + g * 28 + 18 + kc] : 0.0f;

                const float py = (float)(row - PAD + kc / 3) + offy;
                const float pxf= (float)(px  - PAD + kc % 3) + offx;

                const float y0f = floorf(py), x0f = floorf(pxf);
                const int   y0  = (int)y0f,   x0  = (int)x0f;
                const float wy1 = py - y0f,   wx1 = pxf - x0f;
                const float wy0 = 1.0f - wy1, wx0 = 1.0f - wx1;
                const bool vy0 = (y0 >= 0)  & (y0 <  HH);
                const bool vy1 = (y0 >= -1) & (y0 <  HH - 1);
                const bool vx0 = (x0 >= 0)  & (x0 <  WW);
                const bool vx1 = (x0 >= -1) & (x0 <  WW - 1);
                const int yi0 = min(max(y0,     0), HH - 1);
                const int yi1 = min(max(y0 + 1, 0), HH - 1);
                const int xi0 = min(max(x0,     0), WW - 1);
                const int xi1 = min(max(x0 + 1, 0), WW - 1);
                const float my0 = wy0 * m, my1 = wy1 * m;
                const float w00 = (vy0 & vx0) ? my0 * wx0 : 0.0f;
                const float w01 = (vy0 & vx1) ? my0 * wx1 : 0.0f;
                const float w10 = (vy1 & vx0) ? my1 * wx0 : 0.0f;
                const float w11 = (vy1 & vx1) ? my1 * wx1 : 0.0f;

                F16Frag t00, t01, t10, t11;
                t00.q = *(const uint4*)(xg + (size_t)(yi0 * WW + xi0) * 16);
                t01.q = *(const uint4*)(xg + (size_t)(yi0 * WW + xi1) * 16);
                t10.q = *(const uint4*)(xg + (size_t)(yi1 * WW + xi0) * 16);
                t11.q = *(const uint4*)(xg + (size_t)(yi1 * WW + xi1) * 16);

                const _Float16 h00 = (_Float16)w00, h01 = (_Float16)w01;
                const _Float16 h10 = (_Float16)w10, h11 = (_Float16)w11;
                const f16x2 W00 = {h00, h00}, W01 = {h01, h01};
                const f16x2 W10 = {h10, h10}, W11 = {h11, h11};

                F16Frag A;
                #pragma unroll
                for (int d = 0; d < 4; ++d) {
                    f16x2 acc = t00.p[d] * W00;
                    acc += t01.p[d] * W01;
                    acc += t10.p[d] * W10;
                    acc += t11.p[d] * W11;
                    A.p[d] = acc;
                }
                C2 = __builtin_amdgcn_mfma_f32_16x16x32_f16(A.f, B2[s].f, C2, 0, 0, 0);
            }

            #pragma unroll
            for (int r = 0; r < 4; ++r) { gs += C2[r]; gss += C2[r] * C2[r]; }
            cacc[tt] = C2;
        }

        // wave-level deterministic reduction -> per (bg,row) partial
        #pragma unroll
        for (int off = 32; off > 0; off >>= 1) {
            gs  += __shfl_down(gs,  off);
            gss += __shfl_down(gss, off);
        }
        if (lane == 0) {
            const int bg = b * 4 + g;
            partials[(bg * 128 + row) * 2]     = gs;
            partials[(bg * 128 + row) * 2 + 1] = gss;
        }
    }

    __threadfence();
    grid.sync();

    // ================= Phase C: GN stats + apply + exact GELU ===============
    {
        const int bg = b * 4 + wave;
        float s = 0.0f, ss = 0.0f;
        #pragma unroll
        for (int i = 0; i < 2; ++i) {
            const int idx = i * 64 + lane;
            s  += partials[(bg * 128 + idx) * 2];
            ss += partials[(bg * 128 + idx) * 2 + 1];
        }
        #pragma unroll
        for (int off = 32; off > 0; off >>= 1) {
            s  += __shfl_down(s,  off);
            ss += __shfl_down(ss, off);
        }
        if (lane == 0) { smstat[wave * 2] = s; smstat[wave * 2 + 1] = ss; }
        __syncthreads();

        const float n  = (float)(CG * HW);
        const float mu = smstat[g * 2] / n;
        const float rs = rsqrtf(smstat[g * 2 + 1] / n - mu * mu + 1e-5f);
        const int   c  = g * CG + lr;
        const float sw = gn_w[c] * rs;
        const float sb = gn_b[c] - mu * sw;

        float* ob = out + ((size_t)b * 64 + c) * HW + row * WW + lj * 4;
        #pragma unroll
        for (int tt = 0; tt < 8; ++tt) {
            float4 st;
            #pragma unroll
            for (int r = 0; r < 4; ++r) {
                const float t = cacc[tt][r] * sw + sb;
                (&st.x)[r] = t * 0.5f * (1.0f + erff(t * 0.70710678118654752f));
            }
            *(float4*)(ob + tt * 16) = st;
        }
    }
}

// ============================ FALLBACK PATH (R11-proven) =====================

__global__ __launch_bounds__(256, 4) void om_gemm_t(
    const float* __restrict__ x,
    const uint4* __restrict__ frags1,
    const float* __restrict__ b_om,
    const float* __restrict__ offset_scale,
    _Float16* __restrict__ xt4,
    _Float16* __restrict__ om_yx,
    _Float16* __restrict__ om_m)
{
    const int tid  = threadIdx.x;
    const int wave = tid >> 6, lane = tid & 63;
    const int lr   = lane & 15, lj = lane >> 4;
    const int bpix0   = blockIdx.x * 64 + wave * 16;
    const int pixflat = bpix0 + lr;
    const int b       = pixflat >> 14;
    const int pixb    = pixflat & (HW - 1);
    const float scale = offset_scale[0];

    const float* xs = x + (size_t)b * C_IN * HW + pixb;
    F16Frag A0, A1;
    #pragma unroll
    for (int e = 0; e < 8; ++e) A0.h[e] = (_Float16)xs[(size_t)(lj * 8 + e) * HW];
    #pragma unroll
    for (int e = 0; e < 8; ++e) A1.h[e] = (_Float16)xs[(size_t)(32 + lj * 8 + e) * HW];

    const int g0 = (lj >> 1), g1 = 2 + (lj >> 1);
    const int hf = (lj & 1) * 8;
    *(uint4*)(xt4 + ((size_t)(b * 4 + g0) * HW + pixb) * 16 + hf) = A0.q;
    *(uint4*)(xt4 + ((size_t)(b * 4 + g1) * HW + pixb) * 16 + hf) = A1.q;

    int g_[7], oo_[7];
    float bo_[7];
    #pragma unroll
    for (int nt = 0; nt < 7; ++nt) {
        const int col = nt * 16 + lr;
        const int g = col / 28, oo = col - 28 * g;
        g_[nt] = g; oo_[nt] = oo;
        bo_[nt] = (oo < 27) ? b_om[g * 27 + oo] : 0.0f;
    }

    const int bq = bpix0 >> 14;
    const int pq = bpix0 & (HW - 1);
    #pragma unroll
    for (int nt = 0; nt < 7; ++nt) {
        F16Frag B0, B1;
        B0.q = frags1[(nt * 2 + 0) * 64 + lane];
        B1.q = frags1[(nt * 2 + 1) * 64 + lane];
        f32x4 C = {0, 0, 0, 0};
        C = __builtin_amdgcn_mfma_f32_16x16x32_f16(A0.f, B0.f, C, 0, 0, 0);
        C = __builtin_amdgcn_mfma_f32_16x16x32_f16(A1.f, B1.f, C, 0, 0, 0);
        const int g = g_[nt], oo = oo_[nt];
        if (oo < 27) {
            const size_t base = ((size_t)(bq * 4 + g) * HW + pq + lj * 4);
            if (oo < 18) {
                const int k = oo >> 1, comp = oo & 1;
                #pragma unroll
                for (int r = 0; r < 4; ++r)
                    om_yx[((size_t)k * PLANE + base + r) * 2 + comp] =
                        (_Float16)((C[r] + bo_[nt]) * scale);
            } else {
                const int k = oo - 18;
                #pragma unroll
                for (int r = 0; r < 4; ++r)
                    om_m[(size_t)k * PLANE + base + r] =
                        (_Float16)(1.0f / (1.0f + __expf(-(C[r] + bo_[nt]))));
            }
        }
    }
}

__global__ __launch_bounds__(512, 4) void dcn_sample(
    const _Float16* __restrict__ xt4,
    const uint* __restrict__ om_yx_u,
    const _Float16* __restrict__ om_m,
    const uint4* __restrict__ frags2,
    const float* __restrict__ dcn_b,
    float* __restrict__ out,
    float* __restrict__ partials)
{
    const int tid = threadIdx.x;
    const int blk = blockIdx.x;
    const int xcd = blk & 7;
    const int q   = blk >> 3;
    const int bg  = xcd * 2 + (q >> 6);
    const int rp  = q & 63;
    const int r0  = rp * 2;
    const int b   = bg >> 2, g = bg & 3;
    const int wave = tid >> 6, lane = tid & 63;
    const int lr = lane & 15;
    const int lj = lane >> 4;
    const int hsel = lj & 1;
    const int row  = r0 + (wave >> 2);
    const int colw = (wave & 3) * 32;

    __shared__ uint4 sm4[1792];
    __shared__ float red[1024];

    const int wr0 = min(max(r0 - 2, 0), HH - 7);
    {
        const uint4* src = (const uint4*)(xt4 + ((size_t)bg * HW + wr0 * WW) * 16);
        for (int i = tid; i < 1792; i += 512) {
            const int rec = i >> 1;
            const int dst = ((rec >> 7) * 2 + (i & 1)) * 128 + (rec & 127);
            sm4[dst] = src[i];
        }
    }

    F16Frag B2[5];
    #pragma unroll
    for (int s = 0; s < 5; ++s) B2[s].q = frags2[(g * 5 + s) * 64 + lane];
    const float cbias = dcn_b[g * CG + lr];

    const int pbase = (bg << 14) + row * WW + colw + lr;
    uint     yxv[2][5];
    _Float16 mv [2][5];
    #pragma unroll
    for (int t = 0; t < 2; ++t) {
        const int p = pbase + t * 16;
        #pragma unroll
        for (int s = 0; s < 5; ++s) {
            const int kp = 2 * s + (lj >> 1);
            const int kc = (kp < 9) ? kp : 8;
            yxv[t][s] = om_yx_u[(size_t)kc * PLANE + p];
            mv [t][s] = om_m  [(size_t)kc * PLANE + p];
        }
    }

    __syncthreads();
    const _Float16* smh = (const _Float16*)sm4;
    const _Float16* xgf = xt4 + (size_t)bg * HW * 16 + hsel * 8;

    float gs = 0.0f, gss = 0.0f;

    #pragma unroll
    for (int t = 0; t < 2; ++t) {
        const int col0 = colw + t * 16;
        const int pix0 = row * WW + col0;

        f32x4 C2 = {cbias, cbias, cbias, cbias};
        #pragma unroll
        for (int s = 0; s < 5; ++s) {
            const int  kp  = 2 * s + (lj >> 1);
            const bool kok = (kp < 9);
            const int  kc  = kok ? kp : 8;

            YX yx; yx.u = yxv[t][s];
            const float offy = (float)yx.h2[0];
            const float offx = (float)yx.h2[1];
            const float m    = kok ? (float)mv[t][s] : 0.0f;

            const float py = (float)(row       - PAD + kc / 3) + offy;
            const float px = (float)(col0 + lr - PAD + kc % 3) + offx;

            const float y0f = floorf(py), x0f = floorf(px);
            const int   y0  = (int)y0f,   x0  = (int)x0f;
            const float wy1 = py - y0f,   wx1 = px - x0f;
            const float wy0 = 1.0f - wy1, wx0 = 1.0f - wx1;
            const bool vy0 = (y0 >= 0)  & (y0 <  HH);
            const bool vy1 = (y0 >= -1) & (y0 <  HH - 1);
            const bool vx0 = (x0 >= 0)  & (x0 <  WW);
            const bool vx1 = (x0 >= -1) & (x0 <  WW - 1);
            const int yi0 = min(max(y0,     0), HH - 1);
            const int yi1 = min(max(y0 + 1, 0), HH - 1);
            const int xi0 = min(max(x0,     0), WW - 1);
            const int xi1 = min(max(x0 + 1, 0), WW - 1);
            const float my0 = wy0 * m, my1 = wy1 * m;
            const float w00 = (vy0 & vx0) ? my0 * wx0 : 0.0f;
            const float w01 = (vy0 & vx1) ? my0 * wx1 : 0.0f;
            const float w10 = (vy1 & vx0) ? my1 * wx0 : 0.0f;
            const float w11 = (vy1 & vx1) ? my1 * wx1 : 0.0f;

            const int ly0 = yi0 - wr0, ly1 = yi1 - wr0;
            const bool okw = (ly0 >= 0) & (ly1 <= 6);
            const int cy0 = min(max(ly0, 0), 6);
            const int cy1 = min(max(ly1, 0), 6);
            const int rr0 = (cy0 * 2 + hsel) * 128;
            const int rr1 = (cy1 * 2 + hsel) * 128;

            F16Frag t00, t01, t10, t11;
            t00.q = *(const uint4*)(smh + (size_t)(rr0 + xi0) * 8);
            t01.q = *(const uint4*)(smh + (size_t)(rr0 + xi1) * 8);
            t10.q = *(const uint4*)(smh + (size_t)(rr1 + xi0) * 8);
            t11.q = *(const uint4*)(smh + (size_t)(rr1 + xi1) * 8);
            if (!okw) {
                t00.q = *(const uint4*)(xgf + (size_t)(yi0 * WW + xi0) * 16);
                t01.q = *(const uint4*)(xgf + (size_t)(yi0 * WW + xi1) * 16);
                t10.q = *(const uint4*)(xgf + (size_t)(yi1 * WW + xi0) * 16);
                t11.q = *(const uint4*)(xgf + (size_t)(yi1 * WW + xi1) * 16);
            }

            const _Float16 h00 = (_Float16)w00, h01 = (_Float16)w01;
            const _Float16 h10 = (_Float16)w10, h11 = (_Float16)w11;
            const f16x2 W00 = {h00, h00}, W01 = {h01, h01};
            const f16x2 W10 = {h10, h10}, W11 = {h11, h11};

            F16Frag A;
            #pragma unroll
            for (int d = 0; d < 4; ++d) {
                f16x2 acc = t00.p[d] * W00;
                acc += t01.p[d] * W01;
                acc += t10.p[d] * W10;
                acc += t11.p[d] * W11;
                A.p[d] = acc;
            }
            C2 = __builtin_amdgcn_mfma_f32_16x16x32_f16(A.f, B2[s].f, C2, 0, 0, 0);
        }

        float4 st;
        #pragma unroll
        for (int r = 0; r < 4; ++r) {
            const float v = C2[r];
            gs += v; gss += v * v;
            (&st.x)[r] = v;
        }
        *(float4*)(out + ((size_t)b * 64 + g * CG + lr) * HW + pix0 + lj * 4) = st;
    }

    red[tid] = gs; red[512 + tid] = gss;
    __syncthreads();
    for (int st2 = 256; st2 > 0; st2 >>= 1) {
        if (tid < st2) {
            red[tid]       += red[tid + st2];
            red[512 + tid] += red[512 + tid + st2];
        }
        __syncthreads();
    }
    if (tid == 0) {
        partials[(bg * 64 + rp) * 2]     = red[0];
        partials[(bg * 64 + rp) * 2 + 1] = red[512];
    }
}

__global__ __launch_bounds__(256) void gn_gelu2(float* __restrict__ out,
                                                const float* __restrict__ partials,
                                                const float* __restrict__ gn_w,
                                                const float* __restrict__ gn_b)
{
    const int blk = blockIdx.x;
    const int tid = threadIdx.x;
    const int bc  = blk >> 4;
    const int c   = bc & 63;
    const int bg  = ((bc >> 6) << 2) + (c >> 4);

    __shared__ float ls[128];
    if (tid < 128) ls[tid] = partials[bg * 128 + tid];
    __syncthreads();
    #pragma unroll
    for (int st = 64; st >= 2; st >>= 1) {
        if (tid < st) ls[tid] += ls[tid + st];
        __syncthreads();
    }
    const float n  = (float)(CG * HW);
    const float mu = ls[0] / n;
    const float rs = rsqrtf(ls[1] / n - mu * mu + 1e-5f);
    const float sw = gn_w[c] * rs;
    const float sb = gn_b[c] - mu * sw;

    const int idx = blk * 256 + tid;
    float4 v = ((const float4*)out)[idx];
    float rr[4] = {v.x, v.y, v.z, v.w};
    #pragma unroll
    for (int jj = 0; jj < 4; ++jj) {
        const float t = rr[jj] * sw + sb;
        rr[jj] = t * 0.5f * (1.0f + erff(t * 0.70710678118654752f));
    }
    ((float4*)out)[idx] = make_float4(rr[0], rr[1], rr[2], rr[3]);
}

// ============================ launch =========================================

extern "C" void kernel_launch(void* const* d_in, const int* in_sizes, int n_in,
                              void* d_out, int out_size, void* d_ws, size_t ws_size,
                              hipStream_t stream) {
    const float* x            = (const float*)d_in[0];
    const float* w_om         = (const float*)d_in[1];
    const float* b_om         = (const float*)d_in[2];
    const float* dcn_w        = (const float*)d_in[3];
    const float* dcn_b        = (const float*)d_in[4];
    const float* gn_w         = (const float*)d_in[5];
    const float* gn_b         = (const float*)d_in[6];
    const float* offset_scale = (const float*)d_in[7];
    float* out = (float*)d_out;
    char*  ws  = (char*)d_ws;

    _Float16* xt4   = (_Float16*)(ws + XT_OFF);
    _Float16* om_yx = (_Float16*)(ws + OMYX_OFF);
    _Float16* om_m  = (_Float16*)(ws + OMM_OFF);
    uint4* frags1   = (uint4*)(ws + FR1_OFF);
    uint4* frags2   = (uint4*)(ws + FR2_OFF);
    float* partials = (float*)(ws + PART_OFF);

    make_frags<<<9, 256, 0, stream>>>(w_om, dcn_w, frags1, frags2);

    void* args[] = {
        (void*)&x, (void*)&frags1, (void*)&frags2, (void*)&b_om, (void*)&dcn_b,
        (void*)&gn_w, (void*)&gn_b, (void*)&offset_scale, (void*)&xt4,
        (void*)&partials, (void*)&out
    };
    hipError_t err = hipLaunchCooperativeKernel((void*)dcn_coop, dim3(512),
                                                dim3(256), args, 0, stream);
    if (err != hipSuccess) {
        (void)hipGetLastError();   // clear sticky error, use proven R11 path
        om_gemm_t<<<1024, 256, 0, stream>>>(x, frags1, b_om, offset_scale,
                                            xt4, om_yx, om_m);
        dcn_sample<<<1024, 512, 0, stream>>>(xt4, (const uint*)om_yx, om_m,
                                             frags2, dcn_b, out, partials);
        gn_gelu2<<<4096, 256, 0, stream>>>(out, partials, gn_w, gn_b);
    }
}

// Round 15
// 59.276 us; speedup vs baseline: 4.1246x; 4.1246x over previous
//
#include <hip/hip_runtime.h>
#include <math.h>

#define GRP   4
#define K     9
#define PAD   1
#define C_IN  64
#define CG    16
#define HH    128
#define WW    128
#define BB    4
#define HW    (HH*WW)

typedef __attribute__((ext_vector_type(8))) _Float16 f16x8;
typedef __attribute__((ext_vector_type(2))) _Float16 f16x2;
typedef __attribute__((ext_vector_type(4))) float    f32x4;

union F16Frag { f16x8 f; _Float16 h[8]; f16x2 p[4]; uint w[4]; uint4 q; };
union YX      { uint u; f16x2 h2; };

// ---------------- ws layout (R10-compatible) ---------------------------------
#define PLANE      ((size_t)16 * HW)                        // 262,144
#define XT_OFF     0
#define XT_BYTES   ((size_t)16 * HW * 16 * 2)               // 8,388,608
#define OMYX_OFF   XT_BYTES
#define OMYX_BYTES (9 * PLANE * 4)
#define OMM_OFF    (OMYX_OFF + OMYX_BYTES)
#define OMM_BYTES  (9 * PLANE * 2)
#define FR2_OFF    (OMM_OFF + OMM_BYTES)
#define FR2_BYTES  (20 * 64 * 16)
#define PART_OFF   (FR2_OFF + FR2_BYTES)
#define PART_BYTES (2048 * 2 * 4)

// ---- om_gemm_t: transpose-gather + om GEMM -> planar om, group-major xt4 ----
// B1 fragments are built per-block from an LDS-staged w_om (identical values
// to the old make_frags path). Block 0 additionally writes frags2 for
// dcn_sample (visible after the kernel boundary).
__global__ __launch_bounds__(256, 4) void om_gemm_t(
    const float* __restrict__ x,
    const float* __restrict__ w_om,      // [108][64]
    const float* __restrict__ dcn_w,     // [G][16][16][9]
    const float* __restrict__ b_om,
    const float* __restrict__ offset_scale,
    _Float16* __restrict__ xt4,
    _Float16* __restrict__ om_yx,        // [9][PLANE] interleaved y,x
    _Float16* __restrict__ om_m,         // [9][PLANE]
    uint4* __restrict__ frags2)
{
    const int tid  = threadIdx.x;
    const int wave = tid >> 6, lane = tid & 63;
    const int lr   = lane & 15, lj = lane >> 4;
    const int bpix0   = blockIdx.x * 64 + wave * 16;   // flat pixel over B*HW
    const int pixflat = bpix0 + lr;
    const int b       = pixflat >> 14;
    const int pixb    = pixflat & (HW - 1);
    const float scale = offset_scale[0];

    __shared__ float s_wom[108 * 64];    // 27,648 B

    // stage w_om (coalesced)
    for (int i = tid; i < 108 * 64; i += 256) s_wom[i] = w_om[i];

    // block 0 also emits frags2 (dcn weights, packed for dcn_sample)
    if (blockIdx.x == 0) {
        for (int i = tid; i < 20 * 64; i += 256) {
            const int f2 = i >> 6, lane2 = i & 63;
            const int lr2 = lane2 & 15, lj2 = lane2 >> 4;
            const int g = f2 / 5, s = f2 - 5 * g;
            const int kp = 2 * s + (lj2 >> 1);
            const int cib = (lj2 & 1) * 8;
            F16Frag r;
            #pragma unroll
            for (int e = 0; e < 4; ++e) r.w[e] = 0u;
            if (kp < 9) {
                #pragma unroll
                for (int e = 0; e < 8; ++e)
                    r.h[e] = (_Float16)dcn_w[((size_t)(g * CG + lr2) * CG + cib + e) * 9 + kp];
            }
            frags2[f2 * 64 + lane2] = r.q;
        }
    }

    // transpose gather: 16 strided loads -> two fragments
    const float* xs = x + (size_t)b * C_IN * HW + pixb;
    F16Frag A0, A1;
    #pragma unroll
    for (int e = 0; e < 8; ++e) A0.h[e] = (_Float16)xs[(size_t)(lj * 8 + e) * HW];
    #pragma unroll
    for (int e = 0; e < 8; ++e) A1.h[e] = (_Float16)xs[(size_t)(32 + lj * 8 + e) * HW];

    // group-major xt4 write (A0 -> g=lj>>1, A1 -> g=2+(lj>>1), half=(lj&1)*8)
    const int g0 = (lj >> 1), g1 = 2 + (lj >> 1);
    const int hf = (lj & 1) * 8;
    *(uint4*)(xt4 + ((size_t)(b * 4 + g0) * HW + pixb) * 16 + hf) = A0.q;
    *(uint4*)(xt4 + ((size_t)(b * 4 + g1) * HW + pixb) * 16 + hf) = A1.q;

    // per-(lane,nt) metadata
    int g_[7], oo_[7];
    float bo_[7];
    #pragma unroll
    for (int nt = 0; nt < 7; ++nt) {
        const int col = nt * 16 + lr;
        const int g = col / 28, oo = col - 28 * g;
        g_[nt] = g; oo_[nt] = oo;
        bo_[nt] = (oo < 27) ? b_om[g * 27 + oo] : 0.0f;
    }

    __syncthreads();

    const int bq = bpix0 >> 14;
    const int pq = bpix0 & (HW - 1);
    #pragma unroll
    for (int nt = 0; nt < 7; ++nt) {
        const int g = g_[nt], oo = oo_[nt];
        F16Frag B0, B1;
        if (oo < 27) {
            const float* srcw = &s_wom[(g * 27 + oo) * 64];
            #pragma unroll
            for (int e = 0; e < 8; ++e) {
                B0.h[e] = (_Float16)srcw[lj * 8 + e];
                B1.h[e] = (_Float16)srcw[32 + lj * 8 + e];
            }
        } else {
            #pragma unroll
            for (int e = 0; e < 4; ++e) { B0.w[e] = 0u; B1.w[e] = 0u; }
        }
        f32x4 C = {0, 0, 0, 0};
        C = __builtin_amdgcn_mfma_f32_16x16x32_f16(A0.f, B0.f, C, 0, 0, 0);
        C = __builtin_amdgcn_mfma_f32_16x16x32_f16(A1.f, B1.f, C, 0, 0, 0);
        if (oo < 27) {
            const size_t base = ((size_t)(bq * 4 + g) * HW + pq + lj * 4);
            if (oo < 18) {
                const int k = oo >> 1, comp = oo & 1;
                #pragma unroll
                for (int r = 0; r < 4; ++r)
                    om_yx[((size_t)k * PLANE + base + r) * 2 + comp] =
                        (_Float16)((C[r] + bo_[nt]) * scale);
            } else {
                const int k = oo - 18;
                #pragma unroll
                for (int r = 0; r < 4; ++r)
                    om_m[(size_t)k * PLANE + base + r] =
                        (_Float16)(1.0f / (1.0f + __expf(-(C[r] + bo_[nt]))));
            }
        }
    }
}

// ---- dcn_sample: LDS-staged sampling + PV GEMM + GN partials (R10-proven) ---
// 2048 blocks x 4 waves; block = (bg,row). Stage rows wr0..wr0+5 of this bg's
// xt4 plane into LDS as [row][half][xi]; taps read LDS; rare out-of-window
// lanes take a divergent global fixup.
__global__ __launch_bounds__(256, 4) void dcn_sample(
    const _Float16* __restrict__ xt4,
    const uint* __restrict__ om_yx_u,
    const _Float16* __restrict__ om_m,
    const uint4* __restrict__ frags2,
    const float* __restrict__ dcn_b,
    float* __restrict__ out,
    float* __restrict__ partials)
{
    const int tid = threadIdx.x;
    const int blk = blockIdx.x;
    const int xcd = blk & 7;
    const int q   = blk >> 3;            // 0..255
    const int bg  = xcd * 2 + (q >> 7);
    const int row = q & 127;
    const int b   = bg >> 2, g = bg & 3;
    const int wave = tid >> 6, lane = tid & 63;
    const int lr = lane & 15;
    const int lj = lane >> 4;
    const int hsel = lj & 1;

    __shared__ uint4 sm4[1536];          // 6 rows x [half][128 xi] x 16B
    __shared__ float red[512];

    // ---- stage window rows wr0..wr0+5 ----
    const int wr0 = min(max(row - 2, 0), HH - 6);
    {
        const uint4* src = (const uint4*)(xt4 + ((size_t)bg * HW + wr0 * WW) * 16);
        #pragma unroll
        for (int i = tid; i < 1536; i += 256) {
            const int dst = ((i >> 8) * 2 + (i & 1)) * 128 + ((i >> 1) & 127);
            sm4[dst] = src[i];
        }
    }

    F16Frag B2[5];
    #pragma unroll
    for (int s = 0; s < 5; ++s) B2[s].q = frags2[(g * 5 + s) * 64 + lane];
    const float cbias = dcn_b[g * CG + lr];

    // ---- coalesced planar om prefetch for both tiles ----
    const int pbase = (bg << 14) + row * WW + wave * 32 + lr;
    uint     yxv[2][5];
    _Float16 mv [2][5];
    #pragma unroll
    for (int t = 0; t < 2; ++t) {
        const int p = pbase + t * 16;
        #pragma unroll
        for (int s = 0; s < 5; ++s) {
            const int kp = 2 * s + (lj >> 1);
            const int kc = (kp < 9) ? kp : 8;
            yxv[t][s] = om_yx_u[(size_t)kc * PLANE + p];
            mv [t][s] = om_m  [(size_t)kc * PLANE + p];
        }
    }

    __syncthreads();
    const _Float16* smh = (const _Float16*)sm4;
    const _Float16* xgf = xt4 + (size_t)bg * HW * 16 + hsel * 8;

    float gs = 0.0f, gss = 0.0f;

    #pragma unroll
    for (int t = 0; t < 2; ++t) {
        const int col0 = wave * 32 + t * 16;
        const int pix0 = row * WW + col0;

        f32x4 C2 = {cbias, cbias, cbias, cbias};
        #pragma unroll
        for (int s = 0; s < 5; ++s) {
            const int  kp  = 2 * s + (lj >> 1);
            const bool kok = (kp < 9);
            const int  kc  = kok ? kp : 8;

            YX yx; yx.u = yxv[t][s];
            const float offy = (float)yx.h2[0];
            const float offx = (float)yx.h2[1];
            const float m    = kok ? (float)mv[t][s] : 0.0f;

            const float py = (float)(row       - PAD + kc / 3) + offy;
            const float px = (float)(col0 + lr - PAD + kc % 3) + offx;

            const float y0f = floorf(py), x0f = floorf(px);
            const int   y0  = (int)y0f,   x0  = (int)x0f;
            const float wy1 = py - y0f,   wx1 = px - x0f;
            const float wy0 = 1.0f - wy1, wx0 = 1.0f - wx1;
            const bool vy0 = (y0 >= 0)  & (y0 <  HH);
            const bool vy1 = (y0 >= -1) & (y0 <  HH - 1);
            const bool vx0 = (x0 >= 0)  & (x0 <  WW);
            const bool vx1 = (x0 >= -1) & (x0 <  WW - 1);
            const int yi0 = min(max(y0,     0), HH - 1);
            const int yi1 = min(max(y0 + 1, 0), HH - 1);
            const int xi0 = min(max(x0,     0), WW - 1);
            const int xi1 = min(max(x0 + 1, 0), WW - 1);
            const float my0 = wy0 * m, my1 = wy1 * m;
            const float w00 = (vy0 & vx0) ? my0 * wx0 : 0.0f;
            const float w01 = (vy0 & vx1) ? my0 * wx1 : 0.0f;
            const float w10 = (vy1 & vx0) ? my1 * wx0 : 0.0f;
            const float w11 = (vy1 & vx1) ? my1 * wx1 : 0.0f;

            // LDS tap reads (window-clamped); fixup for misses
            const int ly0 = yi0 - wr0, ly1 = yi1 - wr0;
            const bool okw = (ly0 >= 0) & (ly1 <= 5);
            const int cy0 = min(max(ly0, 0), 5);
            const int cy1 = min(max(ly1, 0), 5);
            const int r0 = (cy0 * 2 + hsel) * 128;
            const int r1 = (cy1 * 2 + hsel) * 128;

            F16Frag t00, t01, t10, t11;
            t00.q = *(const uint4*)(smh + (size_t)(r0 + xi0) * 8);
            t01.q = *(const uint4*)(smh + (size_t)(r0 + xi1) * 8);
            t10.q = *(const uint4*)(smh + (size_t)(r1 + xi0) * 8);
            t11.q = *(const uint4*)(smh + (size_t)(r1 + xi1) * 8);
            if (!okw) {   // rare: offsets beyond staged window
                t00.q = *(const uint4*)(xgf + (size_t)(yi0 * WW + xi0) * 16);
                t01.q = *(const uint4*)(xgf + (size_t)(yi0 * WW + xi1) * 16);
                t10.q = *(const uint4*)(xgf + (size_t)(yi1 * WW + xi0) * 16);
                t11.q = *(const uint4*)(xgf + (size_t)(yi1 * WW + xi1) * 16);
            }

            const _Float16 h00 = (_Float16)w00, h01 = (_Float16)w01;
            const _Float16 h10 = (_Float16)w10, h11 = (_Float16)w11;
            const f16x2 W00 = {h00, h00}, W01 = {h01, h01};
            const f16x2 W10 = {h10, h10}, W11 = {h11, h11};

            F16Frag A;
            #pragma unroll
            for (int d = 0; d < 4; ++d) {
                f16x2 acc = t00.p[d] * W00;
                acc += t01.p[d] * W01;
                acc += t10.p[d] * W10;
                acc += t11.p[d] * W11;
                A.p[d] = acc;
            }
            C2 = __builtin_amdgcn_mfma_f32_16x16x32_f16(A.f, B2[s].f, C2, 0, 0, 0);
        }

        float4 st;
        #pragma unroll
        for (int r = 0; r < 4; ++r) {
            const float v = C2[r];
            gs += v; gss += v * v;
            (&st.x)[r] = v;
        }
        *(float4*)(out + ((size_t)b * 64 + g * CG + lr) * HW + pix0 + lj * 4) = st;
    }

    red[tid] = gs; red[256 + tid] = gss;
    __syncthreads();
    for (int st2 = 128; st2 > 0; st2 >>= 1) {
        if (tid < st2) {
            red[tid]       += red[tid + st2];
            red[256 + tid] += red[256 + tid + st2];
        }
        __syncthreads();
    }
    if (tid == 0) {
        partials[(bg * 128 + row) * 2]     = red[0];
        partials[(bg * 128 + row) * 2 + 1] = red[256];
    }
}

// ---- gn_gelu2: fused GN-finalize + apply + exact GELU (R10-proven) ----------
__global__ __launch_bounds__(256) void gn_gelu2(float* __restrict__ out,
                                                const float* __restrict__ partials,
                                                const float* __restrict__ gn_w,
                                                const float* __restrict__ gn_b)
{
    const int blk = blockIdx.x;
    const int tid = threadIdx.x;
    const int bc  = blk >> 4;            // 16 blocks per (b,c)
    const int c   = bc & 63;
    const int bg  = ((bc >> 6) << 2) + (c >> 4);

    __shared__ float ls[256];
    ls[tid] = partials[bg * 256 + tid];
    __syncthreads();
    #pragma unroll
    for (int st = 128; st >= 2; st >>= 1) {      // even strides preserve parity
        if (tid < st) ls[tid] += ls[tid + st];
        __syncthreads();
    }
    const float n  = (float)(CG * HW);
    const float mu = ls[0] / n;
    const float rs = rsqrtf(ls[1] / n - mu * mu + 1e-5f);
    const float sw = gn_w[c] * rs;
    const float sb = gn_b[c] - mu * sw;

    const int idx = blk * 256 + tid;
    float4 v = ((const float4*)out)[idx];
    float rr[4] = {v.x, v.y, v.z, v.w};
    #pragma unroll
    for (int jj = 0; jj < 4; ++jj) {
        const float t = rr[jj] * sw + sb;
        rr[jj] = t * 0.5f * (1.0f + erff(t * 0.70710678118654752f));
    }
    ((float4*)out)[idx] = make_float4(rr[0], rr[1], rr[2], rr[3]);
}

// ============================ launch =========================================

extern "C" void kernel_launch(void* const* d_in, const int* in_sizes, int n_in,
                              void* d_out, int out_size, void* d_ws, size_t ws_size,
                              hipStream_t stream) {
    const float* x            = (const float*)d_in[0];
    const float* w_om         = (const float*)d_in[1];
    const float* b_om         = (const float*)d_in[2];
    const float* dcn_w        = (const float*)d_in[3];
    const float* dcn_b        = (const float*)d_in[4];
    const float* gn_w         = (const float*)d_in[5];
    const float* gn_b         = (const float*)d_in[6];
    const float* offset_scale = (const float*)d_in[7];
    float* out = (float*)d_out;
    char*  ws  = (char*)d_ws;

    _Float16* xt4   = (_Float16*)(ws + XT_OFF);
    _Float16* om_yx = (_Float16*)(ws + OMYX_OFF);
    _Float16* om_m  = (_Float16*)(ws + OMM_OFF);
    uint4* frags2   = (uint4*)(ws + FR2_OFF);
    float* partials = (float*)(ws + PART_OFF);

    om_gemm_t<<<1024, 256, 0, stream>>>(x, w_om, dcn_w, b_om, offset_scale,
                                        xt4, om_yx, om_m, frags2);
    dcn_sample<<<2048, 256, 0, stream>>>(xt4, (const uint*)om_yx, om_m,
                                         frags2, dcn_b, out, partials);
    gn_gelu2<<<4096, 256, 0, stream>>>(out, partials, gn_w, gn_b);
}

// Round 16
// 54.928 us; speedup vs baseline: 4.4511x; 1.0792x over previous
//
#include <hip/hip_runtime.h>
#include <math.h>

#define GRP   4
#define K     9
#define PAD   1
#define C_IN  64
#define CG    16
#define HH    128
#define WW    128
#define BB    4
#define HW    (HH*WW)

typedef __attribute__((ext_vector_type(8))) _Float16 f16x8;
typedef __attribute__((ext_vector_type(2))) _Float16 f16x2;
typedef __attribute__((ext_vector_type(4))) float    f32x4;

union F16Frag { f16x8 f; _Float16 h[8]; f16x2 p[4]; uint w[4]; uint4 q; };
union YX      { uint u; f16x2 h2; };

// ---------------- ws layout --------------------------------------------------
// xt4 group-major fp16 [16 bg][HW][16ch] | om_yx uint planes [9][16*HW] |
// om_m half planes [9][16*HW] | frags | partials
#define PLANE      ((size_t)16 * HW)                        // 262,144
#define XT_OFF     0
#define XT_BYTES   ((size_t)16 * HW * 16 * 2)               // 8,388,608
#define OMYX_OFF   XT_BYTES
#define OMYX_BYTES (9 * PLANE * 4)                          // 9,437,184
#define OMM_OFF    (OMYX_OFF + OMYX_BYTES)
#define OMM_BYTES  (9 * PLANE * 2)                          // 4,718,592
#define FR1_OFF    (OMM_OFF + OMM_BYTES)
#define FR1_BYTES  (14 * 64 * 16)
#define FR2_OFF    (FR1_OFF + FR1_BYTES)
#define FR2_BYTES  (20 * 64 * 16)
#define PART_OFF   (FR2_OFF + FR2_BYTES)
#define PART_BYTES (2048 * 2 * 4)

// ---- make_frags: precompute MFMA weight fragments ---------------------------
__global__ __launch_bounds__(256) void make_frags(const float* __restrict__ w_om,
                                                  const float* __restrict__ dcn_w,
                                                  uint4* __restrict__ frags1,
                                                  uint4* __restrict__ frags2)
{
    const int t    = blockIdx.x * 256 + threadIdx.x;
    const int lane = t & 63;
    const int lr   = lane & 15, lj = lane >> 4;
    const int f    = t >> 6;
    F16Frag r;
    #pragma unroll
    for (int e = 0; e < 4; ++e) r.w[e] = 0u;
    if (f < 14) {                          // frags1: f = nt*2+s
        const int nt = f >> 1, s = f & 1;
        const int col = nt * 16 + lr;
        const int g = col / 28, oo = col - 28 * g;
        if (oo < 27) {
            const float* src = w_om + (size_t)(g * 27 + oo) * C_IN + s * 32 + lj * 8;
            #pragma unroll
            for (int e = 0; e < 8; ++e) r.h[e] = (_Float16)src[e];
        }
        frags1[f * 64 + lane] = r.q;
    } else if (f < 34) {                   // frags2: f-14 = g*5+s
        const int f2 = f - 14;
        const int g = f2 / 5, s = f2 - 5 * g;
        const int kp = 2 * s + (lj >> 1);
        const int cib = (lj & 1) * 8;
        if (kp < 9) {
            #pragma unroll
            for (int e = 0; e < 8; ++e)
                r.h[e] = (_Float16)dcn_w[((size_t)(g * CG + lr) * CG + cib + e) * 9 + kp];
        }
        frags2[f2 * 64 + lane] = r.q;
    }
}

// ---- om_gemm_t: transpose-gather + om GEMM -> planar om, group-major xt4 ----
__global__ __launch_bounds__(256, 4) void om_gemm_t(
    const float* __restrict__ x,
    const uint4* __restrict__ frags1,
    const float* __restrict__ b_om,
    const float* __restrict__ offset_scale,
    _Float16* __restrict__ xt4,
    _Float16* __restrict__ om_yx,     // [9][PLANE] interleaved y,x (2 halfs)
    _Float16* __restrict__ om_m)      // [9][PLANE]
{
    const int tid  = threadIdx.x;
    const int wave = tid >> 6, lane = tid & 63;
    const int lr   = lane & 15, lj = lane >> 4;
    const int bpix0   = blockIdx.x * 64 + wave * 16;   // flat pixel over B*HW
    const int pixflat = bpix0 + lr;
    const int b       = pixflat >> 14;
    const int pixb    = pixflat & (HW - 1);
    const float scale = offset_scale[0];

    // transpose gather: 16 strided loads -> two fragments
    const float* xs = x + (size_t)b * C_IN * HW + pixb;
    F16Frag A0, A1;
    #pragma unroll
    for (int e = 0; e < 8; ++e) A0.h[e] = (_Float16)xs[(size_t)(lj * 8 + e) * HW];
    #pragma unroll
    for (int e = 0; e < 8; ++e) A1.h[e] = (_Float16)xs[(size_t)(32 + lj * 8 + e) * HW];

    // group-major xt4 write (A0 -> g=lj>>1, A1 -> g=2+(lj>>1), half=(lj&1)*8)
    const int g0 = (lj >> 1), g1 = 2 + (lj >> 1);
    const int hf = (lj & 1) * 8;
    *(uint4*)(xt4 + ((size_t)(b * 4 + g0) * HW + pixb) * 16 + hf) = A0.q;
    *(uint4*)(xt4 + ((size_t)(b * 4 + g1) * HW + pixb) * 16 + hf) = A1.q;

    // per-(lane,nt) metadata
    int g_[7], oo_[7];
    float bo_[7];
    #pragma unroll
    for (int nt = 0; nt < 7; ++nt) {
        const int col = nt * 16 + lr;
        const int g = col / 28, oo = col - 28 * g;
        g_[nt] = g; oo_[nt] = oo;
        bo_[nt] = (oo < 27) ? b_om[g * 27 + oo] : 0.0f;
    }

    const int bq = bpix0 >> 14;
    const int pq = bpix0 & (HW - 1);
    #pragma unroll
    for (int nt = 0; nt < 7; ++nt) {
        F16Frag B0, B1;
        B0.q = frags1[(nt * 2 + 0) * 64 + lane];
        B1.q = frags1[(nt * 2 + 1) * 64 + lane];
        f32x4 C = {0, 0, 0, 0};
        C = __builtin_amdgcn_mfma_f32_16x16x32_f16(A0.f, B0.f, C, 0, 0, 0);
        C = __builtin_amdgcn_mfma_f32_16x16x32_f16(A1.f, B1.f, C, 0, 0, 0);
        const int g = g_[nt], oo = oo_[nt];
        if (oo < 27) {
            const size_t base = ((size_t)(bq * 4 + g) * HW + pq + lj * 4);
            if (oo < 18) {
                const int k = oo >> 1, comp = oo & 1;
                #pragma unroll
                for (int r = 0; r < 4; ++r)
                    om_yx[((size_t)k * PLANE + base + r) * 2 + comp] =
                        (_Float16)((C[r] + bo_[nt]) * scale);
            } else {
                const int k = oo - 18;
                #pragma unroll
                for (int r = 0; r < 4; ++r)
                    om_m[(size_t)k * PLANE + base + r] =
                        (_Float16)(1.0f / (1.0f + __expf(-(C[r] + bo_[nt]))));
            }
        }
    }
}

// ---- dcn_sample: LDS-staged sampling + PV GEMM + GN partials ----------------
// 2048 blocks x 4 waves; block = (bg,row). Stage rows wr0..wr0+5 of this bg's
// xt4 plane into LDS as [row][half][xi] (16B records -> 2-way bank = free).
// Taps read LDS; rare out-of-window lanes take a divergent global fixup.
__global__ __launch_bounds__(256, 4) void dcn_sample(
    const _Float16* __restrict__ xt4,
    const uint* __restrict__ om_yx_u,
    const _Float16* __restrict__ om_m,
    const uint4* __restrict__ frags2,
    const float* __restrict__ dcn_b,
    float* __restrict__ out,
    float* __restrict__ partials)
{
    const int tid = threadIdx.x;
    const int blk = blockIdx.x;
    const int xcd = blk & 7;
    const int q   = blk >> 3;            // 0..255
    const int bg  = xcd * 2 + (q >> 7);
    const int row = q & 127;
    const int b   = bg >> 2, g = bg & 3;
    const int wave = tid >> 6, lane = tid & 63;
    const int lr = lane & 15;
    const int lj = lane >> 4;
    const int hsel = lj & 1;

    __shared__ uint4 sm4[1536];          // 6 rows x [half][128 xi] x 16B
    __shared__ float red[512];

    // ---- stage window rows wr0..wr0+5 ----
    const int wr0 = min(max(row - 2, 0), HH - 6);
    {
        const uint4* src = (const uint4*)(xt4 + ((size_t)bg * HW + wr0 * WW) * 16);
        #pragma unroll
        for (int i = tid; i < 1536; i += 256) {
            // src idx i: rec=i>>1 (row r=rec>>7, xi=rec&127), half=i&1
            const int dst = ((i >> 8) * 2 + (i & 1)) * 128 + ((i >> 1) & 127);
            sm4[dst] = src[i];
        }
    }

    F16Frag B2[5];
    #pragma unroll
    for (int s = 0; s < 5; ++s) B2[s].q = frags2[(g * 5 + s) * 64 + lane];
    const float cbias = dcn_b[g * CG + lr];

    // ---- coalesced planar om prefetch for both tiles ----
    const int pbase = (bg << 14) + row * WW + wave * 32 + lr;
    uint     yxv[2][5];
    _Float16 mv [2][5];
    #pragma unroll
    for (int t = 0; t < 2; ++t) {
        const int p = pbase + t * 16;
        #pragma unroll
        for (int s = 0; s < 5; ++s) {
            const int kp = 2 * s + (lj >> 1);
            const int kc = (kp < 9) ? kp : 8;
            yxv[t][s] = om_yx_u[(size_t)kc * PLANE + p];
            mv [t][s] = om_m  [(size_t)kc * PLANE + p];
        }
    }

    __syncthreads();
    const _Float16* smh = (const _Float16*)sm4;
    const _Float16* xgf = xt4 + (size_t)bg * HW * 16 + hsel * 8;

    float gs = 0.0f, gss = 0.0f;

    #pragma unroll
    for (int t = 0; t < 2; ++t) {
        const int col0 = wave * 32 + t * 16;
        const int pix0 = row * WW + col0;

        f32x4 C2 = {cbias, cbias, cbias, cbias};
        #pragma unroll
        for (int s = 0; s < 5; ++s) {
            const int  kp  = 2 * s + (lj >> 1);
            const bool kok = (kp < 9);
            const int  kc  = kok ? kp : 8;

            YX yx; yx.u = yxv[t][s];
            const float offy = (float)yx.h2[0];
            const float offx = (float)yx.h2[1];
            const float m    = kok ? (float)mv[t][s] : 0.0f;

            const float py = (float)(row       - PAD + kc / 3) + offy;
            const float px = (float)(col0 + lr - PAD + kc % 3) + offx;

            const float y0f = floorf(py), x0f = floorf(px);
            const int   y0  = (int)y0f,   x0  = (int)x0f;
            const float wy1 = py - y0f,   wx1 = px - x0f;
            const float wy0 = 1.0f - wy1, wx0 = 1.0f - wx1;
            const bool vy0 = (y0 >= 0)  & (y0 <  HH);
            const bool vy1 = (y0 >= -1) & (y0 <  HH - 1);
            const bool vx0 = (x0 >= 0)  & (x0 <  WW);
            const bool vx1 = (x0 >= -1) & (x0 <  WW - 1);
            const int yi0 = min(max(y0,     0), HH - 1);
            const int yi1 = min(max(y0 + 1, 0), HH - 1);
            const int xi0 = min(max(x0,     0), WW - 1);
            const int xi1 = min(max(x0 + 1, 0), WW - 1);
            const float my0 = wy0 * m, my1 = wy1 * m;
            const float w00 = (vy0 & vx0) ? my0 * wx0 : 0.0f;
            const float w01 = (vy0 & vx1) ? my0 * wx1 : 0.0f;
            const float w10 = (vy1 & vx0) ? my1 * wx0 : 0.0f;
            const float w11 = (vy1 & vx1) ? my1 * wx1 : 0.0f;

            // LDS tap reads (window-clamped); fixup below for misses
            const int ly0 = yi0 - wr0, ly1 = yi1 - wr0;
            const bool okw = (ly0 >= 0) & (ly1 <= 5);
            const int cy0 = min(max(ly0, 0), 5);
            const int cy1 = min(max(ly1, 0), 5);
            const int r0 = (cy0 * 2 + hsel) * 128;
            const int r1 = (cy1 * 2 + hsel) * 128;

            F16Frag t00, t01, t10, t11;
            t00.q = *(const uint4*)(smh + (size_t)(r0 + xi0) * 8);
            t01.q = *(const uint4*)(smh + (size_t)(r0 + xi1) * 8);
            t10.q = *(const uint4*)(smh + (size_t)(r1 + xi0) * 8);
            t11.q = *(const uint4*)(smh + (size_t)(r1 + xi1) * 8);
            if (!okw) {   // rare: offsets beyond staged window
                t00.q = *(const uint4*)(xgf + (size_t)(yi0 * WW + xi0) * 16);
                t01.q = *(const uint4*)(xgf + (size_t)(yi0 * WW + xi1) * 16);
                t10.q = *(const uint4*)(xgf + (size_t)(yi1 * WW + xi0) * 16);
                t11.q = *(const uint4*)(xgf + (size_t)(yi1 * WW + xi1) * 16);
            }

            const _Float16 h00 = (_Float16)w00, h01 = (_Float16)w01;
            const _Float16 h10 = (_Float16)w10, h11 = (_Float16)w11;
            const f16x2 W00 = {h00, h00}, W01 = {h01, h01};
            const f16x2 W10 = {h10, h10}, W11 = {h11, h11};

            F16Frag A;
            #pragma unroll
            for (int d = 0; d < 4; ++d) {
                f16x2 acc = t00.p[d] * W00;
                acc += t01.p[d] * W01;
                acc += t10.p[d] * W10;
                acc += t11.p[d] * W11;
                A.p[d] = acc;
            }
            C2 = __builtin_amdgcn_mfma_f32_16x16x32_f16(A.f, B2[s].f, C2, 0, 0, 0);
        }

        float4 st;
        #pragma unroll
        for (int r = 0; r < 4; ++r) {
            const float v = C2[r];
            gs += v; gss += v * v;
            (&st.x)[r] = v;
        }
        *(float4*)(out + ((size_t)b * 64 + g * CG + lr) * HW + pix0 + lj * 4) = st;
    }

    red[tid] = gs; red[256 + tid] = gss;
    __syncthreads();
    for (int st2 = 128; st2 > 0; st2 >>= 1) {
        if (tid < st2) {
            red[tid]       += red[tid + st2];
            red[256 + tid] += red[256 + tid + st2];
        }
        __syncthreads();
    }
    if (tid == 0) {
        partials[(bg * 128 + row) * 2]     = red[0];
        partials[(bg * 128 + row) * 2 + 1] = red[256];
    }
}

// ---- gn_gelu2: fused GN-finalize + apply + exact GELU -----------------------
__global__ __launch_bounds__(256) void gn_gelu2(float* __restrict__ out,
                                                const float* __restrict__ partials,
                                                const float* __restrict__ gn_w,
                                                const float* __restrict__ gn_b)
{
    const int blk = blockIdx.x;
    const int tid = threadIdx.x;
    const int bc  = blk >> 4;            // 16 blocks per (b,c)
    const int c   = bc & 63;
    const int bg  = ((bc >> 6) << 2) + (c >> 4);

    __shared__ float ls[256];
    ls[tid] = partials[bg * 256 + tid];
    __syncthreads();
    #pragma unroll
    for (int st = 128; st >= 2; st >>= 1) {      // even strides preserve parity
        if (tid < st) ls[tid] += ls[tid + st];
        __syncthreads();
    }
    const float n  = (float)(CG * HW);
    const float mu = ls[0] / n;
    const float rs = rsqrtf(ls[1] / n - mu * mu + 1e-5f);
    const float sw = gn_w[c] * rs;
    const float sb = gn_b[c] - mu * sw;

    const int idx = blk * 256 + tid;
    float4 v = ((const float4*)out)[idx];
    float rr[4] = {v.x, v.y, v.z, v.w};
    #pragma unroll
    for (int jj = 0; jj < 4; ++jj) {
        const float t = rr[jj] * sw + sb;
        rr[jj] = t * 0.5f * (1.0f + erff(t * 0.70710678118654752f));
    }
    ((float4*)out)[idx] = make_float4(rr[0], rr[1], rr[2], rr[3]);
}

// ============================ launch =========================================

extern "C" void kernel_launch(void* const* d_in, const int* in_sizes, int n_in,
                              void* d_out, int out_size, void* d_ws, size_t ws_size,
                              hipStream_t stream) {
    const float* x            = (const float*)d_in[0];
    const float* w_om         = (const float*)d_in[1];
    const float* b_om         = (const float*)d_in[2];
    const float* dcn_w        = (const float*)d_in[3];
    const float* dcn_b        = (const float*)d_in[4];
    const float* gn_w         = (const float*)d_in[5];
    const float* gn_b         = (const float*)d_in[6];
    const float* offset_scale = (const float*)d_in[7];
    float* out = (float*)d_out;
    char*  ws  = (char*)d_ws;

    _Float16* xt4   = (_Float16*)(ws + XT_OFF);
    _Float16* om_yx = (_Float16*)(ws + OMYX_OFF);
    _Float16* om_m  = (_Float16*)(ws + OMM_OFF);
    uint4* frags1   = (uint4*)(ws + FR1_OFF);
    uint4* frags2   = (uint4*)(ws + FR2_OFF);
    float* partials = (float*)(ws + PART_OFF);

    make_frags<<<9, 256, 0, stream>>>(w_om, dcn_w, frags1, frags2);
    om_gemm_t<<<1024, 256, 0, stream>>>(x, frags1, b_om, offset_scale,
                                        xt4, om_yx, om_m);
    dcn_sample<<<2048, 256, 0, stream>>>(xt4, (const uint*)om_yx, om_m,
                                         frags2, dcn_b, out, partials);
    gn_gelu2<<<4096, 256, 0, stream>>>(out, partials, gn_w, gn_b);
}